// Round 2
// baseline (669.703 us; speedup 1.0000x reference)
//
#include <hip/hip_runtime.h>
#include <hip/hip_bf16.h>
#include <math.h>

// Problem constants
#define T_TOK 4096   // B*S tokens
#define D_IN  1024
#define H_DIM 2048
#define O_DIM 1024
#define NE    8
#define ROWCAP 9216  // 8192 routed rows + per-expert pad to 128
#define RT128  72    // ROWCAP/128 row tiles

typedef __bf16 bf16x8 __attribute__((ext_vector_type(8)));
typedef __bf16 bf16x4 __attribute__((ext_vector_type(4)));
typedef float  f32x4  __attribute__((ext_vector_type(4)));

#define ELT(f, j) ((j) == 0 ? (f).x : (j) == 1 ? (f).y : (j) == 2 ? (f).z : (f).w)

// async global->LDS, 16B per lane (HW: wave-uniform base + lane*16)
__device__ __forceinline__ void gl_lds16(const void* g, void* l) {
    __builtin_amdgcn_global_load_lds(
        (const __attribute__((address_space(1))) void*)g,
        (__attribute__((address_space(3))) void*)l, 16, 0, 0);
}

// ---------------- gating: 8 threads/token, fp64 accumulate, shuffle reduce ----------------
__global__ __launch_bounds__(256) void gating_kernel(
    const float* __restrict__ x, const float* __restrict__ Wg, const float* __restrict__ bg,
    __bf16* __restrict__ xb, float* __restrict__ gates_tk, int* __restrict__ idx_tk,
    int* __restrict__ counts, double* __restrict__ prob_part, double* __restrict__ gsum_part)
{
    __shared__ float WgS[8][1032];   // [part][128 dims * 8 experts], +8 pad
    __shared__ float bgS[NE];
    __shared__ double tok_p[32][NE];
    __shared__ double tok_g[32][2];
    __shared__ int    tok_i[32][2];
    const int tid = threadIdx.x;

    for (int i = tid; i < D_IN * NE; i += 256)
        WgS[i >> 10][i & 1023] = Wg[i];
    if (tid < NE) bgS[tid] = bg[tid];

    {
        const size_t base = (size_t)blockIdx.x * 32 * D_IN;
        for (int i = tid * 4; i < 32 * D_IN; i += 256 * 4) {
            float4 v = *(const float4*)(x + base + i);
            bf16x4 b = {(__bf16)v.x, (__bf16)v.y, (__bf16)v.z, (__bf16)v.w};
            *(bf16x4*)(xb + base + i) = b;
        }
    }
    __syncthreads();

    const int tokL = tid >> 3;
    const int part = tid & 7;
    const int t = blockIdx.x * 32 + tokL;
    const float* xr = x + (size_t)t * D_IN + part * 128;

    double s[NE] = {0, 0, 0, 0, 0, 0, 0, 0};
    for (int j = 0; j < 128; j += 4) {
        float4 xv = *(const float4*)(xr + j);
        const float* w = &WgS[part][j * 8];
        #pragma unroll
        for (int jj = 0; jj < 4; ++jj) {
            double xd = (double)(ELT(xv, jj));
            #pragma unroll
            for (int e = 0; e < NE; ++e)
                s[e] += xd * (double)w[jj * 8 + e];
        }
    }
    #pragma unroll
    for (int off = 4; off; off >>= 1)
        #pragma unroll
        for (int e = 0; e < NE; ++e)
            s[e] += __shfl_xor(s[e], off);

    if (part == 0) {
        double rg[NE];
        #pragma unroll
        for (int e = 0; e < NE; ++e) rg[e] = s[e] + (double)bgS[e];
        int i0 = 0;
        #pragma unroll
        for (int e = 1; e < NE; ++e) if (rg[e] > rg[i0]) i0 = e;
        int i1 = -1;
        #pragma unroll
        for (int e = 0; e < NE; ++e) {
            if (e == i0) continue;
            if (i1 < 0 || rg[e] > rg[i1]) i1 = e;
        }
        double e1 = exp(rg[i1] - rg[i0]);
        double den = 1.0 + e1;
        gates_tk[t * 2] = (float)(1.0 / den); gates_tk[t * 2 + 1] = (float)(e1 / den);
        idx_tk[t * 2] = i0;   idx_tk[t * 2 + 1] = i1;
        tok_g[tokL][0] = 1.0 / den; tok_g[tokL][1] = e1 / den;
        tok_i[tokL][0] = i0;        tok_i[tokL][1] = i1;
        double mx = rg[0];
        #pragma unroll
        for (int e = 1; e < NE; ++e) mx = fmax(mx, rg[e]);
        double pe[NE], sum = 0.0;
        #pragma unroll
        for (int e = 0; e < NE; ++e) { pe[e] = exp(rg[e] - mx); sum += pe[e]; }
        #pragma unroll
        for (int e = 0; e < NE; ++e) tok_p[tokL][e] = pe[e] / sum;
    }
    __syncthreads();
    if (tid < NE) {
        double p = 0.0, g = 0.0; int c = 0;
        for (int i = 0; i < 32; ++i) {
            p += tok_p[i][tid];
            if (tok_i[i][0] == tid) { g += tok_g[i][0]; ++c; }
            if (tok_i[i][1] == tid) { g += tok_g[i][1]; ++c; }
        }
        prob_part[blockIdx.x * NE + tid] = p;
        gsum_part[blockIdx.x * NE + tid] = g;
        atomicAdd(&counts[tid], c);
    }
}

// ---------------- weight convert: fp32 -> bf16, same [K][N] layout, fully coalesced ----------------
__global__ __launch_bounds__(256) void cvt_weights(
    const float* __restrict__ W1, const float* __restrict__ W2, const float* __restrict__ W3,
    __bf16* __restrict__ W1b, __bf16* __restrict__ W2b, __bf16* __restrict__ W3b)
{
    const float* src; __bf16* dst; int n8;
    if (blockIdx.z == 0)      { src = W1; dst = W1b; n8 = (NE * D_IN * H_DIM) / 8; }
    else if (blockIdx.z == 1) { src = W2; dst = W2b; n8 = (NE * H_DIM * H_DIM) / 8; }
    else                      { src = W3; dst = W3b; n8 = (NE * H_DIM * O_DIM) / 8; }
    int i = blockIdx.x * 256 + threadIdx.x;
    const int stride = gridDim.x * 256;
    for (; i < n8; i += stride) {
        float4 a = ((const float4*)src)[(size_t)2 * i];
        float4 b = ((const float4*)src)[(size_t)2 * i + 1];
        bf16x8 v = {(__bf16)a.x, (__bf16)a.y, (__bf16)a.z, (__bf16)a.w,
                    (__bf16)b.x, (__bf16)b.y, (__bf16)b.z, (__bf16)b.w};
        *(bf16x8*)(dst + (size_t)i * 8) = v;
    }
}

// ---------------- routing: padded (to 128) prefix sums + tail fill ----------------
__global__ void build_offsets(const int* __restrict__ counts, int* __restrict__ poffset,
                              int* __restrict__ totalp, int* __restrict__ token_ids)
{
    __shared__ int po[NE + 1];
    __shared__ int cnt[NE];
    const int tid = threadIdx.x;
    if (tid == 0) {
        po[0] = 0;
        for (int e = 0; e < NE; ++e) {
            cnt[e] = counts[e];
            int pc = (cnt[e] + 127) & ~127;
            po[e + 1] = po[e] + pc;
        }
        for (int e = 0; e <= NE; ++e) poffset[e] = po[e];
        totalp[0] = po[NE];
    }
    __syncthreads();
    for (int e = 0; e < NE; ++e) {
        int base = po[e], c = cnt[e], pc = po[e + 1] - po[e];
        for (int i = c + tid; i < pc; i += 64) token_ids[base + i] = 0;
    }
}

__global__ __launch_bounds__(256) void scatter_rows(
    const int* __restrict__ idx_tk, const int* __restrict__ poffset,
    int* __restrict__ cursors, int* __restrict__ token_ids, int* __restrict__ t2r)
{
    int t = blockIdx.x * 256 + threadIdx.x;
    if (t >= T_TOK) return;
    for (int k = 0; k < 2; ++k) {
        int e = idx_tk[t * 2 + k];
        int pos = atomicAdd(&cursors[e], 1);
        int r = poffset[e] + pos;
        token_ids[r] = t;
        t2r[t * 2 + k] = r;
    }
}

// ---------------- expert GEMM: 128x128 tile, BK=64, fused bf16 B transpose ----------------
// A (bf16 [rows][K]): global_load_lds, source-swizzled chunks, key = row&7.
// B (bf16 [K][N] per expert): reg-staged (8 x bf16x4 per thread = 8k x 4n block),
//   in-register transpose, swizzled ds_write_b128 per output n-row.
//   Swizzle key(n) = (n&7) ^ ((n>>4)&3): write side spans all 8 perms (4-way, ~free);
//   read side: fragment j has (n>>4)&3 == j, so pB = pA ^ j (2-way, free).
// XCD swizzle: XCD x owns n-tile(s) {x, x+8}, walks row-tiles in order -> B panel
//   (512KB bf16) stays L2-resident per XCD; B fetched ~once from HBM.
template<bool GATHER, bool RELU, bool OUTBF16>
__global__ __launch_bounds__(256) void gemm_expert(
    const __bf16* __restrict__ A, int lda,
    const __bf16* __restrict__ Bw, int Kdim, int N,
    const float* __restrict__ bias,
    void* __restrict__ Out, int ldo,
    const int* __restrict__ token_ids,
    const int* __restrict__ poffset,
    const int* __restrict__ totalp)
{
    __shared__ __bf16 As[128 * 64];
    __shared__ __bf16 Bs[128 * 64];
    const int tid = threadIdx.x;

    // XCD-aware remap: flat % 8 = XCD class; each class takes contiguous idx range,
    // decoded as (n-tile, row-tile) with n-tile slowest -> B panel locality per XCD.
    const int NYg = gridDim.y;
    const int flat = blockIdx.y * gridDim.x + blockIdx.x;
    const int xcd = flat & 7, idx = flat >> 3;
    const int lbx = xcd + 8 * (idx / NYg);
    const int lby = idx % NYg;

    const int row0 = lby * 128;
    if (row0 >= totalp[0]) return;
    int e = 0;
    while (e < NE - 1 && row0 >= poffset[e + 1]) ++e;
    const int n0 = lbx * 128;
    const __bf16* Be = Bw + (size_t)e * Kdim * N;
    const float* biase = bias + (size_t)e * N;

    // A staging geometry (global_load_lds, source-swizzled chunks)
    const int srow = tid >> 3;
    const int jperm = (tid & 7) ^ (srow & 7);   // XOR-swizzled source chunk
    const int scol = jperm * 8;                 // element offset within 64-wide K slice
    int arow_g[4];
    #pragma unroll
    for (int c = 0; c < 4; ++c) {
        int r = row0 + c * 32 + srow;
        arow_g[c] = GATHER ? token_ids[r] : r;
    }

    // B staging geometry (fused transpose, bf16)
    const int rg = tid >> 5;                    // k-octet 0..7
    const int cB = tid & 31;                    // n-quad
    const __bf16* bsrc0 = Be + (size_t)rg * 8 * N + n0 + cB * 4;

    const int lane = tid & 63;
    const int quad = lane >> 4;
    const int m16  = lane & 15;
    const int wave = tid >> 6;
    const int wm = wave >> 1, wn = wave & 1;

    f32x4 acc[4][4];
    #pragma unroll
    for (int i = 0; i < 4; ++i)
        #pragma unroll
        for (int j = 0; j < 4; ++j)
            acc[i][j] = (f32x4){0.f, 0.f, 0.f, 0.f};

    const int niter = Kdim >> 6;

    // prologue: load B tile 0 into registers (8 rows x 4 cols bf16)
    bf16x4 r[8];
    #pragma unroll
    for (int i = 0; i < 8; ++i)
        r[i] = *(const bf16x4*)(bsrc0 + (size_t)i * N);

    for (int kt = 0; kt < niter; ++kt) {
        const int kofs = kt * 64 + scol;
        #pragma unroll
        for (int c = 0; c < 4; ++c)
            gl_lds16(A + (size_t)arow_g[c] * lda + kofs, (char*)As + c * 4096 + tid * 16);
        // transpose current B regs -> swizzled LDS
        #pragma unroll
        for (int j = 0; j < 4; ++j) {
            const int n = cB * 4 + j;
            const int key = (n & 7) ^ ((n >> 4) & 3);
            bf16x8 v;
            #pragma unroll
            for (int i = 0; i < 8; ++i) v[i] = r[i][j];
            *(bf16x8*)&Bs[n * 64 + ((rg ^ key) << 3)] = v;
        }
        __syncthreads();
        // prefetch next B tile into registers; latency hides under MFMA cluster
        if (kt + 1 < niter) {
            const __bf16* bsrc = bsrc0 + (size_t)(kt + 1) * 64 * N;
            #pragma unroll
            for (int i = 0; i < 8; ++i)
                r[i] = *(const bf16x4*)(bsrc + (size_t)i * N);
        }
        #pragma unroll
        for (int ks = 0; ks < 2; ++ks) {
            const int c0 = (ks << 2) | quad;
            const int pA = c0 ^ (m16 & 7);
            bf16x8 af[4], bfr[4];
            #pragma unroll
            for (int i = 0; i < 4; ++i)
                af[i] = *(const bf16x8*)&As[(wm * 64 + i * 16 + m16) * 64 + pA * 8];
            #pragma unroll
            for (int j = 0; j < 4; ++j) {
                const int pB = pA ^ j;
                bfr[j] = *(const bf16x8*)&Bs[(wn * 64 + j * 16 + m16) * 64 + pB * 8];
            }
            #pragma unroll
            for (int i = 0; i < 4; ++i)
                #pragma unroll
                for (int j = 0; j < 4; ++j)
                    acc[i][j] = __builtin_amdgcn_mfma_f32_16x16x32_bf16(af[i], bfr[j], acc[i][j], 0, 0, 0);
        }
        __syncthreads();
    }
    #pragma unroll
    for (int i = 0; i < 4; ++i)
        #pragma unroll
        for (int j = 0; j < 4; ++j)
            #pragma unroll
            for (int rr = 0; rr < 4; ++rr) {
                int grow = row0 + wm * 64 + i * 16 + quad * 4 + rr;
                int gcol = n0 + wn * 64 + j * 16 + m16;
                float v = acc[i][j][rr] + biase[gcol];
                if (RELU) v = v > 0.f ? v : 0.f;
                if (OUTBF16) ((__bf16*)Out)[(size_t)grow * ldo + gcol] = (__bf16)v;
                else         ((float*)Out)[(size_t)grow * ldo + gcol] = v;
            }
}

// ---------------- combine: out[t] = g0*y[r0] + g1*y[r1] ----------------
__global__ __launch_bounds__(256) void combine_out(
    const float* __restrict__ y, const float* __restrict__ gates_tk,
    const int* __restrict__ t2r, float* __restrict__ out)
{
    const int t = blockIdx.x;
    const int o = threadIdx.x * 4;
    const int r0 = t2r[t * 2], r1 = t2r[t * 2 + 1];
    const float g0 = gates_tk[t * 2], g1 = gates_tk[t * 2 + 1];
    float4 a = *(const float4*)&y[(size_t)r0 * O_DIM + o];
    float4 b = *(const float4*)&y[(size_t)r1 * O_DIM + o];
    float4 c;
    c.x = g0 * a.x + g1 * b.x;
    c.y = g0 * a.y + g1 * b.y;
    c.z = g0 * a.z + g1 * b.z;
    c.w = g0 * a.w + g1 * b.w;
    *(float4*)&out[(size_t)t * O_DIM + o] = c;
}

// ---------------- finalize aux outputs ----------------
__global__ void finalize_kernel(const double* __restrict__ prob_part,
                                const double* __restrict__ gsum_part,
                                float* __restrict__ out)
{
    __shared__ double ps[NE], gs[NE];
    const int tid = threadIdx.x;
    if (tid < NE) {
        double p = 0.0, g = 0.0;
        for (int b = 0; b < 128; ++b) {
            p += prob_part[b * NE + tid];
            g += gsum_part[b * NE + tid];
        }
        ps[tid] = p / (double)T_TOK;
        gs[tid] = g / (double)T_TOK;
        out[(size_t)T_TOK * O_DIM + 1 + tid] = (float)(g / (double)T_TOK);
    }
    __syncthreads();
    if (tid == 0) {
        double lb = 0.0, ent = 0.0;
        for (int e = 0; e < NE; ++e) {
            lb += ps[e] * gs[e];
            ent -= ps[e] * log(ps[e] + 1e-8);
        }
        out[(size_t)T_TOK * O_DIM] = (float)(0.01 * 8.0 * lb);
        out[(size_t)T_TOK * O_DIM + 9] = (float)ent;
    }
}

// ---------------- launch ----------------
extern "C" void kernel_launch(void* const* d_in, const int* in_sizes, int n_in,
                              void* d_out, int out_size, void* d_ws, size_t ws_size,
                              hipStream_t stream)
{
    const float* x  = (const float*)d_in[0];
    const float* Wg = (const float*)d_in[1];
    const float* bg = (const float*)d_in[2];
    const float* W1 = (const float*)d_in[3];
    const float* b1 = (const float*)d_in[4];
    const float* W2 = (const float*)d_in[5];
    const float* b2 = (const float*)d_in[6];
    const float* W3 = (const float*)d_in[7];
    const float* b3 = (const float*)d_in[8];
    float* out = (float*)d_out;
    char* ws = (char*)d_ws;

    size_t off = 0;
    __bf16* xb  = (__bf16*)(ws + off); off += (size_t)T_TOK * D_IN * 2;
    __bf16* h1  = (__bf16*)(ws + off);
    float*  y   = (float*) (ws + off); off += (size_t)ROWCAP * H_DIM * 2;
    __bf16* h2  = (__bf16*)(ws + off); off += (size_t)ROWCAP * H_DIM * 2;
    __bf16* W1b = (__bf16*)(ws + off); off += (size_t)NE * D_IN * H_DIM * 2;
    __bf16* W2b = (__bf16*)(ws + off); off += (size_t)NE * H_DIM * H_DIM * 2;
    __bf16* W3b = (__bf16*)(ws + off); off += (size_t)NE * H_DIM * O_DIM * 2;
    float* gates_tk = (float*)(ws + off); off += T_TOK * 2 * 4;
    int* idx_tk     = (int*)(ws + off);   off += T_TOK * 2 * 4;
    int* t2r        = (int*)(ws + off);   off += T_TOK * 2 * 4;
    int* token_ids  = (int*)(ws + off);   off += ROWCAP * 4;
    double* prob_part = (double*)(ws + off); off += 128 * NE * 8;
    double* gsum_part = (double*)(ws + off); off += 128 * NE * 8;
    char* small     = ws + off;
    int* counts     = (int*)(small + 0);
    int* cursors    = (int*)(small + 32);
    int* poffset    = (int*)(small + 64);
    int* totalp     = (int*)(small + 112);

    hipMemsetAsync(small, 0, 256, stream);
    gating_kernel<<<128, 256, 0, stream>>>(x, Wg, bg, xb, gates_tk, idx_tk,
                                           counts, prob_part, gsum_part);
    cvt_weights<<<dim3(1024, 1, 3), 256, 0, stream>>>(W1, W2, W3, W1b, W2b, W3b);
    build_offsets<<<1, 64, 0, stream>>>(counts, poffset, totalp, token_ids);
    scatter_rows<<<16, 256, 0, stream>>>(idx_tk, poffset, cursors, token_ids, t2r);
    gemm_expert<true,  true,  true ><<<dim3(H_DIM / 128, RT128), 256, 0, stream>>>(
        xb, D_IN, W1b, D_IN, H_DIM, b1, (void*)h1, H_DIM, token_ids, poffset, totalp);
    gemm_expert<false, true,  true ><<<dim3(H_DIM / 128, RT128), 256, 0, stream>>>(
        h1, H_DIM, W2b, H_DIM, H_DIM, b2, (void*)h2, H_DIM, token_ids, poffset, totalp);
    gemm_expert<false, false, false><<<dim3(O_DIM / 128, RT128), 256, 0, stream>>>(
        h2, H_DIM, W3b, H_DIM, O_DIM, b3, (void*)y, O_DIM, token_ids, poffset, totalp);
    combine_out<<<T_TOK, 256, 0, stream>>>(y, gates_tk, t2r, out);
    finalize_kernel<<<1, 64, 0, stream>>>(prob_part, gsum_part, out);
}

// Round 3
// 574.196 us; speedup vs baseline: 1.1663x; 1.1663x over previous
//
#include <hip/hip_runtime.h>
#include <hip/hip_bf16.h>
#include <math.h>

// Problem constants
#define T_TOK 4096   // B*S tokens
#define D_IN  1024
#define H_DIM 2048
#define O_DIM 1024
#define NE    8
#define ROWCAP 9216  // 8192 routed rows + per-expert pad to 128
#define RT128  72    // ROWCAP/128 row tiles

typedef __bf16 bf16x8 __attribute__((ext_vector_type(8)));
typedef __bf16 bf16x4 __attribute__((ext_vector_type(4)));
typedef float  f32x4  __attribute__((ext_vector_type(4)));

#define ELT(f, j) ((j) == 0 ? (f).x : (j) == 1 ? (f).y : (j) == 2 ? (f).z : (f).w)

// async global->LDS, 16B per lane (HW: wave-uniform base + lane*16)
__device__ __forceinline__ void gl_lds16(const void* g, void* l) {
    __builtin_amdgcn_global_load_lds(
        (const __attribute__((address_space(1))) void*)g,
        (__attribute__((address_space(3))) void*)l, 16, 0, 0);
}

// ---------------- gating: 8 threads/token, fp64 accumulate, shuffle reduce ----------------
// Writes PER-BLOCK partials (counts/probs/gatesums) -> no atomics, no memset needed.
__global__ __launch_bounds__(256) void gating_kernel(
    const float* __restrict__ x, const float* __restrict__ Wg, const float* __restrict__ bg,
    __bf16* __restrict__ xb, float* __restrict__ gates_tk, int* __restrict__ idx_tk,
    int* __restrict__ cnt_part, double* __restrict__ prob_part, double* __restrict__ gsum_part)
{
    __shared__ float WgS[8][1032];   // [part][128 dims * 8 experts], +8 pad
    __shared__ float bgS[NE];
    __shared__ double tok_p[32][NE];
    __shared__ double tok_g[32][2];
    __shared__ int    tok_i[32][2];
    const int tid = threadIdx.x;

    for (int i = tid; i < D_IN * NE; i += 256)
        WgS[i >> 10][i & 1023] = Wg[i];
    if (tid < NE) bgS[tid] = bg[tid];

    {
        const size_t base = (size_t)blockIdx.x * 32 * D_IN;
        for (int i = tid * 4; i < 32 * D_IN; i += 256 * 4) {
            float4 v = *(const float4*)(x + base + i);
            bf16x4 b = {(__bf16)v.x, (__bf16)v.y, (__bf16)v.z, (__bf16)v.w};
            *(bf16x4*)(xb + base + i) = b;
        }
    }
    __syncthreads();

    const int tokL = tid >> 3;
    const int part = tid & 7;
    const int t = blockIdx.x * 32 + tokL;
    const float* xr = x + (size_t)t * D_IN + part * 128;

    double s[NE] = {0, 0, 0, 0, 0, 0, 0, 0};
    for (int j = 0; j < 128; j += 4) {
        float4 xv = *(const float4*)(xr + j);
        const float* w = &WgS[part][j * 8];
        #pragma unroll
        for (int jj = 0; jj < 4; ++jj) {
            double xd = (double)(ELT(xv, jj));
            #pragma unroll
            for (int e = 0; e < NE; ++e)
                s[e] += xd * (double)w[jj * 8 + e];
        }
    }
    #pragma unroll
    for (int off = 4; off; off >>= 1)
        #pragma unroll
        for (int e = 0; e < NE; ++e)
            s[e] += __shfl_xor(s[e], off);

    if (part == 0) {
        double rg[NE];
        #pragma unroll
        for (int e = 0; e < NE; ++e) rg[e] = s[e] + (double)bgS[e];
        int i0 = 0;
        #pragma unroll
        for (int e = 1; e < NE; ++e) if (rg[e] > rg[i0]) i0 = e;
        int i1 = -1;
        #pragma unroll
        for (int e = 0; e < NE; ++e) {
            if (e == i0) continue;
            if (i1 < 0 || rg[e] > rg[i1]) i1 = e;
        }
        double e1 = exp(rg[i1] - rg[i0]);
        double den = 1.0 + e1;
        gates_tk[t * 2] = (float)(1.0 / den); gates_tk[t * 2 + 1] = (float)(e1 / den);
        idx_tk[t * 2] = i0;   idx_tk[t * 2 + 1] = i1;
        tok_g[tokL][0] = 1.0 / den; tok_g[tokL][1] = e1 / den;
        tok_i[tokL][0] = i0;        tok_i[tokL][1] = i1;
        double mx = rg[0];
        #pragma unroll
        for (int e = 1; e < NE; ++e) mx = fmax(mx, rg[e]);
        double pe[NE], sum = 0.0;
        #pragma unroll
        for (int e = 0; e < NE; ++e) { pe[e] = exp(rg[e] - mx); sum += pe[e]; }
        #pragma unroll
        for (int e = 0; e < NE; ++e) tok_p[tokL][e] = pe[e] / sum;
    }
    __syncthreads();
    if (tid < NE) {
        double p = 0.0, g = 0.0; int c = 0;
        for (int i = 0; i < 32; ++i) {
            p += tok_p[i][tid];
            if (tok_i[i][0] == tid) { g += tok_g[i][0]; ++c; }
            if (tok_i[i][1] == tid) { g += tok_g[i][1]; ++c; }
        }
        prob_part[blockIdx.x * NE + tid] = p;
        gsum_part[blockIdx.x * NE + tid] = g;
        cnt_part[blockIdx.x * NE + tid] = c;
    }
}

// ---------------- routing: deterministic scan-based scatter (replaces memset+offsets+scatter) ----
// 16 blocks x 256 threads; block b handles tokens [b*256, b*256+256).
// Per-expert position = global poffset + prefix over earlier gating blocks + in-block scan.
// Counts packed 8 x 16-bit in int4 for a single Hillis-Steele scan (max 512 < 2^16).
__global__ __launch_bounds__(256) void route_tokens(
    const int* __restrict__ cnt_part, const int* __restrict__ idx_tk,
    int* __restrict__ poffset, int* __restrict__ totalp,
    int* __restrict__ token_ids, int* __restrict__ t2r)
{
    __shared__ int cntE[NE], baseE[NE];
    __shared__ int po[NE + 1];
    __shared__ int4 sb[256];
    const int tid = threadIdx.x;
    const int b = blockIdx.x;

    if (tid < NE) {
        int tot = 0, pre = 0;
        for (int g = 0; g < 128; ++g) {
            int v = cnt_part[g * NE + tid];
            tot += v;
            if (g < b * 8) pre += v;
        }
        cntE[tid] = tot;
        baseE[tid] = pre;
    }
    __syncthreads();
    if (tid == 0) {
        po[0] = 0;
        for (int e = 0; e < NE; ++e) po[e + 1] = po[e] + ((cntE[e] + 127) & ~127);
        if (b == 0) {
            for (int e = 0; e <= NE; ++e) poffset[e] = po[e];
            totalp[0] = po[NE];
        }
    }
    __syncthreads();

    const int t = b * 256 + tid;
    const int e0 = idx_tk[t * 2], e1 = idx_tk[t * 2 + 1];
    int4 p = {0, 0, 0, 0};
    ((int*)&p)[e0 >> 1] += 1 << ((e0 & 1) * 16);
    ((int*)&p)[e1 >> 1] += 1 << ((e1 & 1) * 16);
    sb[tid] = p;
    __syncthreads();
    for (int off = 1; off < 256; off <<= 1) {
        int4 v = sb[tid];
        int4 u = {0, 0, 0, 0};
        if (tid >= off) u = sb[tid - off];
        __syncthreads();
        v.x += u.x; v.y += u.y; v.z += u.z; v.w += u.w;
        sb[tid] = v;
        __syncthreads();
    }
    int4 inc = sb[tid];
    // position of this token's assignment to expert e = inclusive(e) - 1 (own contribution is 1)
    {
        int pos0 = ((((const int*)&inc)[e0 >> 1] >> ((e0 & 1) * 16)) & 0xffff) - 1;
        int r0 = po[e0] + baseE[e0] + pos0;
        token_ids[r0] = t; t2r[t * 2] = r0;
        int pos1 = ((((const int*)&inc)[e1 >> 1] >> ((e1 & 1) * 16)) & 0xffff) - 1;
        int r1 = po[e1] + baseE[e1] + pos1;
        token_ids[r1] = t; t2r[t * 2 + 1] = r1;
    }
    // pad fill: rows [cnt, padded) per expert -> token 0
    for (int e = 0; e < NE; ++e) {
        int c = cntE[e], base = po[e], pc = po[e + 1] - po[e];
        for (int i = c + b * 256 + tid; i < pc; i += 16 * 256) token_ids[base + i] = 0;
    }
}

// ---------------- expert GEMM: 128x128 tile, BK=64, fused fp32->bf16 B transpose ----------------
// A (bf16 [rows][K]): global_load_lds, source-swizzled chunks, key = row&7.
// B (fp32 [K][N] per expert): reg-staged 8k x 4n float4 block per thread, convert+transpose
//   in registers, swizzled ds_write_b128. key(n) = (n&7) ^ ((n>>4)&3): write side spans all
//   8 perms (4-way, ~free); read side pB = pA ^ j (verified round 2).
// Natural block order (n-tile fastest): 16 blocks of one row-tile run concurrently ->
//   A slab shared in L2 (round-0-verified 175MB); n-tile -> fixed XCD gives B affinity.
template<bool GATHER, bool RELU, bool OUTBF16>
__global__ __launch_bounds__(256) void gemm_expert(
    const __bf16* __restrict__ A, int lda,
    const float* __restrict__ Bw, int Kdim, int N,
    const float* __restrict__ bias,
    void* __restrict__ Out, int ldo,
    const int* __restrict__ token_ids,
    const int* __restrict__ poffset,
    const int* __restrict__ totalp)
{
    __shared__ __bf16 As[128 * 64];
    __shared__ __bf16 Bs[128 * 64];
    const int tid = threadIdx.x;
    const int row0 = blockIdx.y * 128;
    if (row0 >= totalp[0]) return;
    int e = 0;
    while (e < NE - 1 && row0 >= poffset[e + 1]) ++e;
    const int n0 = blockIdx.x * 128;
    const float* Be = Bw + (size_t)e * Kdim * N;
    const float* biase = bias + (size_t)e * N;

    // A staging geometry (global_load_lds, source-swizzled chunks)
    const int srow = tid >> 3;
    const int jperm = (tid & 7) ^ (srow & 7);   // XOR-swizzled source chunk
    const int scol = jperm * 8;                 // element offset within 64-wide K slice
    int arow_g[4];
    #pragma unroll
    for (int c = 0; c < 4; ++c) {
        int r = row0 + c * 32 + srow;
        arow_g[c] = GATHER ? token_ids[r] : r;
    }

    // B staging geometry (fused transpose+convert, fp32 source)
    const int rg = tid >> 5;                    // k-octet 0..7
    const int cB = tid & 31;                    // n-quad
    const float* bsrc0 = Be + (size_t)rg * 8 * N + n0 + cB * 4;

    const int lane = tid & 63;
    const int quad = lane >> 4;
    const int m16  = lane & 15;
    const int wave = tid >> 6;
    const int wm = wave >> 1, wn = wave & 1;

    f32x4 acc[4][4];
    #pragma unroll
    for (int i = 0; i < 4; ++i)
        #pragma unroll
        for (int j = 0; j < 4; ++j)
            acc[i][j] = (f32x4){0.f, 0.f, 0.f, 0.f};

    const int niter = Kdim >> 6;

    // prologue: load B tile 0 into registers (8 k-rows x 4 n-cols fp32)
    float4 r[8];
    #pragma unroll
    for (int i = 0; i < 8; ++i)
        r[i] = *(const float4*)(bsrc0 + (size_t)i * N);

    for (int kt = 0; kt < niter; ++kt) {
        const int kofs = kt * 64 + scol;
        #pragma unroll
        for (int c = 0; c < 4; ++c)
            gl_lds16(A + (size_t)arow_g[c] * lda + kofs, (char*)As + c * 4096 + tid * 16);
        // convert+transpose current B regs -> swizzled LDS
        #pragma unroll
        for (int j = 0; j < 4; ++j) {
            const int n = cB * 4 + j;
            const int key = (n & 7) ^ ((n >> 4) & 3);
            bf16x8 v;
            #pragma unroll
            for (int i = 0; i < 8; ++i) v[i] = (__bf16)(ELT(r[i], j));
            *(bf16x8*)&Bs[n * 64 + ((rg ^ key) << 3)] = v;
        }
        __syncthreads();
        // prefetch next B tile into registers; latency hides under MFMA cluster
        if (kt + 1 < niter) {
            const float* bsrc = bsrc0 + (size_t)(kt + 1) * 64 * N;
            #pragma unroll
            for (int i = 0; i < 8; ++i)
                r[i] = *(const float4*)(bsrc + (size_t)i * N);
        }
        #pragma unroll
        for (int ks = 0; ks < 2; ++ks) {
            const int c0 = (ks << 2) | quad;
            const int pA = c0 ^ (m16 & 7);
            bf16x8 af[4], bfr[4];
            #pragma unroll
            for (int i = 0; i < 4; ++i)
                af[i] = *(const bf16x8*)&As[(wm * 64 + i * 16 + m16) * 64 + pA * 8];
            #pragma unroll
            for (int j = 0; j < 4; ++j) {
                const int pB = pA ^ j;
                bfr[j] = *(const bf16x8*)&Bs[(wn * 64 + j * 16 + m16) * 64 + pB * 8];
            }
            #pragma unroll
            for (int i = 0; i < 4; ++i)
                #pragma unroll
                for (int j = 0; j < 4; ++j)
                    acc[i][j] = __builtin_amdgcn_mfma_f32_16x16x32_bf16(af[i], bfr[j], acc[i][j], 0, 0, 0);
        }
        __syncthreads();
    }
    #pragma unroll
    for (int i = 0; i < 4; ++i)
        #pragma unroll
        for (int j = 0; j < 4; ++j)
            #pragma unroll
            for (int rr = 0; rr < 4; ++rr) {
                int grow = row0 + wm * 64 + i * 16 + quad * 4 + rr;
                int gcol = n0 + wn * 64 + j * 16 + m16;
                float v = acc[i][j][rr] + biase[gcol];
                if (RELU) v = v > 0.f ? v : 0.f;
                if (OUTBF16) ((__bf16*)Out)[(size_t)grow * ldo + gcol] = (__bf16)v;
                else         ((float*)Out)[(size_t)grow * ldo + gcol] = v;
            }
}

// ---------------- combine (+ finalize in block 0): out[t] = g0*y[r0] + g1*y[r1] ----------------
__global__ __launch_bounds__(256) void combine_out(
    const float* __restrict__ y, const float* __restrict__ gates_tk,
    const int* __restrict__ t2r, float* __restrict__ out,
    const double* __restrict__ prob_part, const double* __restrict__ gsum_part)
{
    const int t = blockIdx.x;
    const int o = threadIdx.x * 4;
    const int r0 = t2r[t * 2], r1 = t2r[t * 2 + 1];
    const float g0 = gates_tk[t * 2], g1 = gates_tk[t * 2 + 1];
    float4 a = *(const float4*)&y[(size_t)r0 * O_DIM + o];
    float4 b = *(const float4*)&y[(size_t)r1 * O_DIM + o];
    float4 c;
    c.x = g0 * a.x + g1 * b.x;
    c.y = g0 * a.y + g1 * b.y;
    c.z = g0 * a.z + g1 * b.z;
    c.w = g0 * a.w + g1 * b.w;
    *(float4*)&out[(size_t)t * O_DIM + o] = c;

    if (blockIdx.x == 0) {
        __shared__ double ps[NE], gs[NE];
        const int tid = threadIdx.x;
        if (tid < NE) {
            double p = 0.0, g = 0.0;
            for (int bb = 0; bb < 128; ++bb) {
                p += prob_part[bb * NE + tid];
                g += gsum_part[bb * NE + tid];
            }
            ps[tid] = p / (double)T_TOK;
            gs[tid] = g / (double)T_TOK;
            out[(size_t)T_TOK * O_DIM + 1 + tid] = (float)(g / (double)T_TOK);
        }
        __syncthreads();
        if (tid == 0) {
            double lb = 0.0, ent = 0.0;
            for (int e = 0; e < NE; ++e) {
                lb += ps[e] * gs[e];
                ent -= ps[e] * log(ps[e] + 1e-8);
            }
            out[(size_t)T_TOK * O_DIM] = (float)(0.01 * 8.0 * lb);
            out[(size_t)T_TOK * O_DIM + 9] = (float)ent;
        }
    }
}

// ---------------- launch: 6 dispatches (was 10) ----------------
extern "C" void kernel_launch(void* const* d_in, const int* in_sizes, int n_in,
                              void* d_out, int out_size, void* d_ws, size_t ws_size,
                              hipStream_t stream)
{
    const float* x  = (const float*)d_in[0];
    const float* Wg = (const float*)d_in[1];
    const float* bg = (const float*)d_in[2];
    const float* W1 = (const float*)d_in[3];
    const float* b1 = (const float*)d_in[4];
    const float* W2 = (const float*)d_in[5];
    const float* b2 = (const float*)d_in[6];
    const float* W3 = (const float*)d_in[7];
    const float* b3 = (const float*)d_in[8];
    float* out = (float*)d_out;
    char* ws = (char*)d_ws;

    size_t off = 0;
    __bf16* xb  = (__bf16*)(ws + off); off += (size_t)T_TOK * D_IN * 2;
    __bf16* h1  = (__bf16*)(ws + off);
    float*  y   = (float*) (ws + off); off += (size_t)ROWCAP * H_DIM * 2;
    __bf16* h2  = (__bf16*)(ws + off); off += (size_t)ROWCAP * H_DIM * 2;
    float* gates_tk = (float*)(ws + off); off += T_TOK * 2 * 4;
    int* idx_tk     = (int*)(ws + off);   off += T_TOK * 2 * 4;
    int* t2r        = (int*)(ws + off);   off += T_TOK * 2 * 4;
    int* token_ids  = (int*)(ws + off);   off += ROWCAP * 4;
    double* prob_part = (double*)(ws + off); off += 128 * NE * 8;
    double* gsum_part = (double*)(ws + off); off += 128 * NE * 8;
    int* cnt_part   = (int*)(ws + off);   off += 128 * NE * 4;
    int* poffset    = (int*)(ws + off);   off += (NE + 1) * 4;
    int* totalp     = (int*)(ws + off);   off += 16;

    gating_kernel<<<128, 256, 0, stream>>>(x, Wg, bg, xb, gates_tk, idx_tk,
                                           cnt_part, prob_part, gsum_part);
    route_tokens<<<16, 256, 0, stream>>>(cnt_part, idx_tk, poffset, totalp, token_ids, t2r);
    gemm_expert<true,  true,  true ><<<dim3(H_DIM / 128, RT128), 256, 0, stream>>>(
        xb, D_IN, W1, D_IN, H_DIM, b1, (void*)h1, H_DIM, token_ids, poffset, totalp);
    gemm_expert<false, true,  true ><<<dim3(H_DIM / 128, RT128), 256, 0, stream>>>(
        h1, H_DIM, W2, H_DIM, H_DIM, b2, (void*)h2, H_DIM, token_ids, poffset, totalp);
    gemm_expert<false, false, false><<<dim3(O_DIM / 128, RT128), 256, 0, stream>>>(
        h2, H_DIM, W3, H_DIM, O_DIM, b3, (void*)y, O_DIM, token_ids, poffset, totalp);
    combine_out<<<T_TOK, 256, 0, stream>>>(y, gates_tk, t2r, out, prob_part, gsum_part);
}